// Round 1
// baseline (202.458 us; speedup 1.0000x reference)
//
#include <hip/hip_runtime.h>
#include <hip/hip_bf16.h>
#include <stdint.h>

#define DEVI __device__ __forceinline__

typedef __attribute__((ext_vector_type(4))) float f32x4;
typedef __attribute__((ext_vector_type(16))) float f32x16;
typedef __attribute__((ext_vector_type(8))) short bf16x8;

constexpr int nB = 2, nN = 1024, nD = 512, nH = 16, nDH = 32;

DEVI unsigned short f2bf(float x) {
  unsigned u = __float_as_uint(x);
  return (unsigned short)((u + 0x7fffu + ((u >> 16) & 1u)) >> 16);
}
DEVI unsigned pk2(float lo, float hi_) {
  return (unsigned)f2bf(lo) | ((unsigned)f2bf(hi_) << 16);
}
DEVI float bperm(int srclane, float v) {
  return __int_as_float(__builtin_amdgcn_ds_bpermute(srclane << 2, __float_as_int(v)));
}

// ---------------- 1. f32 -> bf16 conversion (x, att_w, ff_w) ----------------
// float4 units: x 262144, att_w 196608, ff_w 65536 -> total 524288
__global__ __launch_bounds__(256) void cvt_kernel(const float* __restrict__ x,
                                                  const float* __restrict__ aw,
                                                  const float* __restrict__ fw,
                                                  unsigned short* __restrict__ xb,
                                                  unsigned short* __restrict__ awb,
                                                  unsigned short* __restrict__ fwb) {
  int i = blockIdx.x * 256 + threadIdx.x;
  const float* src; unsigned short* dst; int base;
  if (i < 262144)      { src = x;  dst = xb;  base = i; }
  else if (i < 458752) { src = aw; dst = awb; base = i - 262144; }
  else                 { src = fw; dst = fwb; base = i - 458752; }
  float4 v = reinterpret_cast<const float4*>(src)[base];
  ushort4 o;
  o.x = f2bf(v.x); o.y = f2bf(v.y); o.z = f2bf(v.z); o.w = f2bf(v.w);
  reinterpret_cast<ushort4*>(dst)[base] = o;
}

// ---------------- 2/4. bf16 B^T GEMM: C[m,f] = sum_k A[m,k]*Bw[f,k] ----------
// MODE 0: scatter qkv -> q/k [B,H,N,32], v transposed [B,H,32,N]
// MODE 1: plain f32 store to C [M, Ncols]
template <int BM, int BN, int MODE>
__global__ __launch_bounds__(256) void gemm_bt(const unsigned short* __restrict__ A,
                                               const unsigned short* __restrict__ Bw,
                                               unsigned short* __restrict__ q,
                                               unsigned short* __restrict__ kmat,
                                               unsigned short* __restrict__ vt,
                                               float* __restrict__ C,
                                               int K, int Ncols) {
  constexpr int MW = BM / 2, NW = BN / 2;   // per-wave tile (2x2 waves)
  constexpr int MF = MW / 16, NF = NW / 16;
  __shared__ __align__(16) unsigned short sA[BM * 32];
  __shared__ __align__(16) unsigned short sB[BN * 32];
  const int tid = threadIdx.x, wid = tid >> 6, lane = tid & 63;
  const int wr = wid >> 1, wc = wid & 1;
  const long rowA = (long)blockIdx.x * BM;
  const long rowB = (long)blockIdx.y * BN;

  f32x4 acc[MF][NF];
#pragma unroll
  for (int mm = 0; mm < MF; ++mm)
#pragma unroll
    for (int nn = 0; nn < NF; ++nn)
#pragma unroll
      for (int r = 0; r < 4; ++r) acc[mm][nn][r] = 0.f;

  for (int k0 = 0; k0 < K; k0 += 32) {
    __syncthreads();
#pragma unroll
    for (int c = 0; c < BM / 64; ++c) {
      int off = (tid + 256 * c) * 8;
      int r = off >> 5, s8 = off & 31;
      *reinterpret_cast<uint4*>(&sA[off]) =
          *reinterpret_cast<const uint4*>(&A[(rowA + r) * K + k0 + s8]);
    }
#pragma unroll
    for (int c = 0; c < BN / 64; ++c) {
      int off = (tid + 256 * c) * 8;
      int r = off >> 5, s8 = off & 31;
      *reinterpret_cast<uint4*>(&sB[off]) =
          *reinterpret_cast<const uint4*>(&Bw[(rowB + r) * K + k0 + s8]);
    }
    __syncthreads();
    const int kg = (lane >> 4) * 8, rlo = lane & 15;
    bf16x8 af[MF], bfv[NF];
#pragma unroll
    for (int mm = 0; mm < MF; ++mm)
      af[mm] = *reinterpret_cast<const bf16x8*>(&sA[(MW * wr + 16 * mm + rlo) * 32 + kg]);
#pragma unroll
    for (int nn = 0; nn < NF; ++nn)
      bfv[nn] = *reinterpret_cast<const bf16x8*>(&sB[(NW * wc + 16 * nn + rlo) * 32 + kg]);
#pragma unroll
    for (int mm = 0; mm < MF; ++mm)
#pragma unroll
      for (int nn = 0; nn < NF; ++nn)
        acc[mm][nn] = __builtin_amdgcn_mfma_f32_16x16x32_bf16(af[mm], bfv[nn],
                                                              acc[mm][nn], 0, 0, 0);
  }

#pragma unroll
  for (int mm = 0; mm < MF; ++mm)
#pragma unroll
    for (int nn = 0; nn < NF; ++nn)
#pragma unroll
      for (int r = 0; r < 4; ++r) {
        float v = acc[mm][nn][r];
        int row = (int)rowA + MW * wr + 16 * mm + (lane >> 4) * 4 + r;
        int col = (int)rowB + NW * wc + 16 * nn + (lane & 15);
        if constexpr (MODE == 0) {
          int s = col >> 9, rem = col & 511;
          int h = rem >> 5, d = rem & 31;
          int b = row >> 10, n = row & 1023;
          unsigned short bv = f2bf(v);
          if (s == 0)
            q[((long)(b * nH + h) * nN + n) * nDH + d] = bv;
          else if (s == 1)
            kmat[((long)(b * nH + h) * nN + n) * nDH + d] = bv;
          else
            vt[((long)(b * nH + h) * nDH + d) * nN + n] = bv;
        } else {
          C[(long)row * Ncols + col] = v;
        }
      }
}

// ---------------- 3. fused attention ----------------------------------------
// grid.x = B * N/32 (b, i-tile), grid.y = H/4; WG = 4 waves = 4 heads.
// Swapped QK^T: S^T[j,i] via mfma(K,Q); lane (i=lane&31, hi=lane>>5) owns
// column i, 16 j's: j = (r&3) + 8*(r>>2) + 4*hi.
__global__ __launch_bounds__(256) void attn_kernel(
    const unsigned short* __restrict__ q, const unsigned short* __restrict__ kmat,
    const unsigned short* __restrict__ vt,
    const float* __restrict__ pdist, const float* __restrict__ angle,
    const float* __restrict__ adj, const unsigned char* __restrict__ mask,
    const float* __restrict__ gamma_p, const float* __restrict__ gamma_adj,
    const float* __restrict__ w_bias, unsigned short* __restrict__ att) {
  const int b = blockIdx.x >> 5;
  const int ibase = (blockIdx.x & 31) * 32;
  const int tid = threadIdx.x, wid = tid >> 6, lane = tid & 63;
  const int h = blockIdx.y * 4 + wid;
  const int li = lane & 31, hi = lane >> 5;

  __shared__ float s_pd[32][33], s_a0[32][33], s_a1[32][33], s_adj[32][33];
  __shared__ float s_mk[32];

  const float gp = gamma_p[h], ga = gamma_adj[h];
  const float wb0 = w_bias[2 * h], wb1 = w_bias[2 * h + 1];

  const unsigned short* qb = q + ((long)(b * nH + h) * nN + ibase) * nDH;
  const bf16x8 qf0 = *reinterpret_cast<const bf16x8*>(qb + li * 32 + hi * 8);
  const bf16x8 qf1 = *reinterpret_cast<const bf16x8*>(qb + li * 32 + 16 + hi * 8);

  f32x16 o;
#pragma unroll
  for (int r = 0; r < 16; ++r) o[r] = 0.f;
  float mrun = -INFINITY, lrun = 0.f;

  for (int jt = 0; jt < 32; ++jt) {
    const int jbase = jt * 32;
    __syncthreads();
    // ---- stage bias tiles (shared across the 4 heads) ----
    if (tid < 64) {  // pdist: 32 rows x 128B, 2 threads/row
      int r = tid >> 1, c = (tid & 1) * 16;
      const float4* s4 = reinterpret_cast<const float4*>(
          pdist + ((long)b * nN + ibase + r) * nN + jbase + c);
#pragma unroll
      for (int u = 0; u < 4; ++u) {
        float4 v = s4[u];
        s_pd[r][c + 4 * u]     = v.x; s_pd[r][c + 4 * u + 1] = v.y;
        s_pd[r][c + 4 * u + 2] = v.z; s_pd[r][c + 4 * u + 3] = v.w;
      }
    } else if (tid < 128) {  // adj
      int t2 = tid - 64;
      int r = t2 >> 1, c = (t2 & 1) * 16;
      const float4* s4 = reinterpret_cast<const float4*>(
          adj + ((long)b * nN + ibase + r) * nN + jbase + c);
#pragma unroll
      for (int u = 0; u < 4; ++u) {
        float4 v = s4[u];
        s_adj[r][c + 4 * u]     = v.x; s_adj[r][c + 4 * u + 1] = v.y;
        s_adj[r][c + 4 * u + 2] = v.z; s_adj[r][c + 4 * u + 3] = v.w;
      }
    } else {  // angle (interleaved c=2): 128 threads, 4/row, 8 j-pairs each
      int t2 = tid - 128;
      int r = t2 >> 2, c8 = (t2 & 3) * 8;
      const float4* s4 = reinterpret_cast<const float4*>(
          angle + (((long)b * nN + ibase + r) * nN + jbase + c8) * 2);
#pragma unroll
      for (int u = 0; u < 4; ++u) {
        float4 v = s4[u];
        s_a0[r][c8 + 2 * u]     = v.x; s_a1[r][c8 + 2 * u]     = v.y;
        s_a0[r][c8 + 2 * u + 1] = v.z; s_a1[r][c8 + 2 * u + 1] = v.w;
      }
    }
    if (tid < 32) s_mk[tid] = mask[b * nN + jbase + tid] ? -1e9f : 0.f;
    __syncthreads();

    // ---- S^T = K_tile * Q_tile^T ----
    const unsigned short* kb = kmat + ((long)(b * nH + h) * nN + jbase) * nDH;
    bf16x8 kf0 = *reinterpret_cast<const bf16x8*>(kb + li * 32 + hi * 8);
    bf16x8 kf1 = *reinterpret_cast<const bf16x8*>(kb + li * 32 + 16 + hi * 8);
    f32x16 z;
#pragma unroll
    for (int r = 0; r < 16; ++r) z[r] = 0.f;
    f32x16 sc = __builtin_amdgcn_mfma_f32_32x32x16_bf16(kf0, qf0, z, 0, 0, 0);
    sc = __builtin_amdgcn_mfma_f32_32x32x16_bf16(kf1, qf1, sc, 0, 0, 0);

    // ---- scale + biases + mask, tile max ----
    float sv[16];
    float tmax = -INFINITY;
#pragma unroll
    for (int r = 0; r < 16; ++r) {
      const int joff = (r & 3) + 8 * (r >> 2) + 4 * hi;
      float xv = sc[r] * 0.1767766952966369f
                 - gp * s_pd[li][joff] + wb0 * s_a0[li][joff] + wb1 * s_a1[li][joff]
                 + ga * s_adj[li][joff] + s_mk[joff];
      sv[r] = xv;
      tmax = fmaxf(tmax, xv);
    }
    tmax = fmaxf(tmax, __shfl_xor(tmax, 32));
    const float mnew = fmaxf(mrun, tmax);
    const float alpha = __expf(mrun - mnew);
    float p[16];
    float psum = 0.f;
#pragma unroll
    for (int r = 0; r < 16; ++r) { p[r] = __expf(sv[r] - mnew); psum += p[r]; }
    psum += __shfl_xor(psum, 32);
    lrun = lrun * alpha + psum;
    mrun = mnew;

    // ---- rescale O rows (alpha broadcast from lane i) ----
#pragma unroll
    for (int r = 0; r < 16; ++r) {
      const int irow = (r & 3) + 8 * (r >> 2) + 4 * hi;
      o[r] *= bperm(irow, alpha);
    }

    // ---- P -> bf16 A-fragments (half-exchange via shfl_xor 32) ----
    unsigned ow[8], rw[8];
#pragma unroll
    for (int t = 0; t < 8; ++t) ow[t] = pk2(p[2 * t], p[2 * t + 1]);
#pragma unroll
    for (int t = 0; t < 8; ++t) rw[t] = __shfl_xor(ow[t], 32);
    union U { unsigned u[4]; bf16x8 v; };
    U u0, u1;
    if (hi == 0) {
      u0.u[0] = ow[0]; u0.u[1] = ow[1]; u0.u[2] = rw[0]; u0.u[3] = rw[1];
      u1.u[0] = ow[4]; u1.u[1] = ow[5]; u1.u[2] = rw[4]; u1.u[3] = rw[5];
    } else {
      u0.u[0] = rw[2]; u0.u[1] = rw[3]; u0.u[2] = ow[2]; u0.u[3] = ow[3];
      u1.u[0] = rw[6]; u1.u[1] = rw[7]; u1.u[2] = ow[6]; u1.u[3] = ow[7];
    }

    // ---- PV: O[i,d] += P * V ----
    const unsigned short* vb = vt + ((long)(b * nH + h) * nDH + li) * nN + jbase;
    bf16x8 vf0 = *reinterpret_cast<const bf16x8*>(vb + hi * 8);
    bf16x8 vf1 = *reinterpret_cast<const bf16x8*>(vb + 16 + hi * 8);
    o = __builtin_amdgcn_mfma_f32_32x32x16_bf16(u0.v, vf0, o, 0, 0, 0);
    o = __builtin_amdgcn_mfma_f32_32x32x16_bf16(u1.v, vf1, o, 0, 0, 0);
  }

  const float linv = 1.f / lrun;
#pragma unroll
  for (int r = 0; r < 16; ++r) {
    const int irow = (r & 3) + 8 * (r >> 2) + 4 * hi;
    float v = o[r] * bperm(irow, linv);
    att[((long)b * nN + ibase + irow) * nD + h * nDH + li] = f2bf(v);
  }
}

// ---------------- 5. residual + bias + LayerNorm ----------------------------
__global__ __launch_bounds__(256) void ln_kernel(const float* __restrict__ x,
                                                 const float* __restrict__ ffc,
                                                 const float* __restrict__ ffb,
                                                 const float* __restrict__ lnw,
                                                 const float* __restrict__ lnb,
                                                 float* __restrict__ out) {
  const int row = blockIdx.x, tid = threadIdx.x;
  const int wid = tid >> 6, lane = tid & 63;
  const int c = tid * 2;
  const long base = (long)row * nD + c;
  float2 xv = *reinterpret_cast<const float2*>(x + base);
  float2 cv = *reinterpret_cast<const float2*>(ffc + base);
  float2 bv = *reinterpret_cast<const float2*>(ffb + c);
  float y0 = xv.x + cv.x + bv.x, y1 = xv.y + cv.y + bv.y;
  float s = y0 + y1, s2 = y0 * y0 + y1 * y1;
#pragma unroll
  for (int off = 1; off < 64; off <<= 1) {
    s += __shfl_xor(s, off);
    s2 += __shfl_xor(s2, off);
  }
  __shared__ float red[8];
  if (lane == 0) { red[wid] = s; red[4 + wid] = s2; }
  __syncthreads();
  s = red[0] + red[1] + red[2] + red[3];
  s2 = red[4] + red[5] + red[6] + red[7];
  const float mu = s * (1.f / nD);
  const float var = s2 * (1.f / nD) - mu * mu;
  const float rs = rsqrtf(var + 1e-5f);
  float2 wv = *reinterpret_cast<const float2*>(lnw + c);
  float2 lv = *reinterpret_cast<const float2*>(lnb + c);
  float2 ov;
  ov.x = (y0 - mu) * rs * wv.x + lv.x;
  ov.y = (y1 - mu) * rs * wv.y + lv.y;
  *reinterpret_cast<float2*>(out + base) = ov;
}

// ---------------- launch -----------------------------------------------------
extern "C" void kernel_launch(void* const* d_in, const int* in_sizes, int n_in,
                              void* d_out, int out_size, void* d_ws, size_t ws_size,
                              hipStream_t stream) {
  const float* x         = (const float*)d_in[0];
  const float* pdist     = (const float*)d_in[1];
  const float* angle     = (const float*)d_in[2];
  const float* adj       = (const float*)d_in[3];
  const unsigned char* mask = (const unsigned char*)d_in[4];
  const float* gamma_p   = (const float*)d_in[5];
  const float* gamma_adj = (const float*)d_in[6];
  const float* w_bias    = (const float*)d_in[7];
  const float* att_w     = (const float*)d_in[8];
  const float* ff_w      = (const float*)d_in[9];
  const float* ff_b      = (const float*)d_in[10];
  const float* ln_w      = (const float*)d_in[11];
  const float* ln_b      = (const float*)d_in[12];
  float* out = (float*)d_out;

  char* ws = (char*)d_ws;
  unsigned short* xb   = (unsigned short*)(ws);                          // 2 MB
  unsigned short* awb  = (unsigned short*)(ws + (2u << 20));             // 1.5 MB
  unsigned short* fwb  = (unsigned short*)(ws + (2u << 20) + (3u << 19)); // 0.5 MB
  unsigned short* qm   = (unsigned short*)(ws + (4u << 20));             // 2 MB
  unsigned short* km   = (unsigned short*)(ws + (6u << 20));             // 2 MB
  unsigned short* vtm  = (unsigned short*)(ws + (8u << 20));             // 2 MB
  unsigned short* attb = (unsigned short*)(ws + (10u << 20));            // 2 MB
  float* ffc           = (float*)(ws + (12u << 20));                     // 4 MB

  hipLaunchKernelGGL(cvt_kernel, dim3(2048), dim3(256), 0, stream,
                     x, att_w, ff_w, xb, awb, fwb);
  hipLaunchKernelGGL((gemm_bt<128, 128, 0>), dim3(16, 12), dim3(256), 0, stream,
                     xb, awb, qm, km, vtm, nullptr, 512, 0);
  hipLaunchKernelGGL(attn_kernel, dim3(64, 4), dim3(256), 0, stream,
                     qm, km, vtm, pdist, angle, adj, mask,
                     gamma_p, gamma_adj, w_bias, attb);
  hipLaunchKernelGGL((gemm_bt<64, 128, 1>), dim3(32, 4), dim3(256), 0, stream,
                     attb, fwb, nullptr, nullptr, nullptr, ffc, 512, 512);
  hipLaunchKernelGGL(ln_kernel, dim3(2048), dim3(256), 0, stream,
                     x, ffc, ff_b, ln_w, ln_b, out);
}

// Round 2
// 155.561 us; speedup vs baseline: 1.3015x; 1.3015x over previous
//
#include <hip/hip_runtime.h>
#include <hip/hip_bf16.h>
#include <stdint.h>

#define DEVI __device__ __forceinline__

typedef __attribute__((ext_vector_type(4))) float f32x4;
typedef __attribute__((ext_vector_type(16))) float f32x16;
typedef __attribute__((ext_vector_type(8))) short bf16x8;

constexpr int nB = 2, nN = 1024, nD = 512, nH = 16, nDH = 32;

DEVI unsigned short f2bf(float x) {
  unsigned u = __float_as_uint(x);
  return (unsigned short)((u + 0x7fffu + ((u >> 16) & 1u)) >> 16);
}
DEVI float bf2f(unsigned short s) { return __uint_as_float(((unsigned)s) << 16); }
DEVI unsigned pk2(float lo, float hi_) {
  return (unsigned)f2bf(lo) | ((unsigned)f2bf(hi_) << 16);
}
DEVI float bperm(int srclane, float v) {
  return __int_as_float(__builtin_amdgcn_ds_bpermute(srclane << 2, __float_as_int(v)));
}
DEVI void gload16(const void* g, void* l) {
  __builtin_amdgcn_global_load_lds((const __attribute__((address_space(1))) void*)g,
                                   (__attribute__((address_space(3))) void*)l, 16, 0, 0);
}

// ---------------- 1. f32 -> bf16 conversion (x, att_w, ff_w) ----------------
__global__ __launch_bounds__(256) void cvt_kernel(const float* __restrict__ x,
                                                  const float* __restrict__ aw,
                                                  const float* __restrict__ fw,
                                                  unsigned short* __restrict__ xb,
                                                  unsigned short* __restrict__ awb,
                                                  unsigned short* __restrict__ fwb) {
  int i = blockIdx.x * 256 + threadIdx.x;
  const float* src; unsigned short* dst; int base;
  if (i < 262144)      { src = x;  dst = xb;  base = i; }
  else if (i < 458752) { src = aw; dst = awb; base = i - 262144; }
  else                 { src = fw; dst = fwb; base = i - 458752; }
  float4 v = reinterpret_cast<const float4*>(src)[base];
  ushort4 o;
  o.x = f2bf(v.x); o.y = f2bf(v.y); o.z = f2bf(v.z); o.w = f2bf(v.w);
  reinterpret_cast<ushort4*>(dst)[base] = o;
}

// ---------------- 2/5. bf16 B^T GEMM with global_load_lds staging ------------
// MODE 0: scatter qkv -> q (scaled by 1/sqrt(32)) / k / v, all [B,H,N,32]
// MODE 1: plain f32 store to C [M, Ncols]
template <int BM, int BN, int MODE>
__global__ __launch_bounds__(256) void gemm_bt(const unsigned short* __restrict__ A,
                                               const unsigned short* __restrict__ Bw,
                                               unsigned short* __restrict__ q,
                                               unsigned short* __restrict__ kmat,
                                               unsigned short* __restrict__ vm,
                                               float* __restrict__ C,
                                               int K, int Ncols) {
  constexpr int MW = BM / 2, NW = BN / 2;
  constexpr int MF = MW / 16, NF = NW / 16;
  constexpr int IA = BM / 16, IB = BN / 16, PW = (IA + IB) / 4;
  __shared__ __align__(16) unsigned short sA[BM * 32];
  __shared__ __align__(16) unsigned short sB[BN * 32];
  const int tid = threadIdx.x, wid = tid >> 6, lane = tid & 63;
  const int wr = wid >> 1, wc = wid & 1;
  const long rowA = (long)blockIdx.x * BM;
  const long rowB = (long)blockIdx.y * BN;
  const int srow = lane >> 2, scol = (lane & 3) * 8;

  f32x4 acc[MF][NF];
#pragma unroll
  for (int mm = 0; mm < MF; ++mm)
#pragma unroll
    for (int nn = 0; nn < NF; ++nn)
#pragma unroll
      for (int r = 0; r < 4; ++r) acc[mm][nn][r] = 0.f;

  for (int k0 = 0; k0 < K; k0 += 32) {
    __syncthreads();
#pragma unroll
    for (int j = 0; j < PW; ++j) {
      int g = wid + 4 * j;
      if (g < IA) {
        gload16(&A[(rowA + g * 16 + srow) * K + k0 + scol], &sA[g * 512]);
      } else {
        int c = g - IA;
        gload16(&Bw[(rowB + c * 16 + srow) * K + k0 + scol], &sB[c * 512]);
      }
    }
    __syncthreads();
    const int kg = (lane >> 4) * 8, rlo = lane & 15;
    bf16x8 af[MF], bfv[NF];
#pragma unroll
    for (int mm = 0; mm < MF; ++mm)
      af[mm] = *reinterpret_cast<const bf16x8*>(&sA[(MW * wr + 16 * mm + rlo) * 32 + kg]);
#pragma unroll
    for (int nn = 0; nn < NF; ++nn)
      bfv[nn] = *reinterpret_cast<const bf16x8*>(&sB[(NW * wc + 16 * nn + rlo) * 32 + kg]);
#pragma unroll
    for (int mm = 0; mm < MF; ++mm)
#pragma unroll
      for (int nn = 0; nn < NF; ++nn)
        acc[mm][nn] = __builtin_amdgcn_mfma_f32_16x16x32_bf16(af[mm], bfv[nn],
                                                              acc[mm][nn], 0, 0, 0);
  }

#pragma unroll
  for (int mm = 0; mm < MF; ++mm)
#pragma unroll
    for (int nn = 0; nn < NF; ++nn)
#pragma unroll
      for (int r = 0; r < 4; ++r) {
        float v = acc[mm][nn][r];
        int row = (int)rowA + MW * wr + 16 * mm + (lane >> 4) * 4 + r;
        int col = (int)rowB + NW * wc + 16 * nn + (lane & 15);
        if constexpr (MODE == 0) {
          int s = col >> 9, rem = col & 511;
          int h = rem >> 5, d = rem & 31;
          int b = row >> 10, n = row & 1023;
          long idx = ((long)(b * nH + h) * nN + n) * nDH + d;
          if (s == 0)      q[idx]    = f2bf(v * 0.1767766952966369f);
          else if (s == 1) kmat[idx] = f2bf(v);
          else             vm[idx]   = f2bf(v);
        } else {
          C[(long)row * Ncols + col] = v;
        }
      }
}

// ---------------- 3. V transpose: [B,H,N,32] -> per-j-tile [d][j] blocks -----
// vtt[(bh*32 + jt)*1024 + d*32 + j_local]
__global__ __launch_bounds__(256) void vtrans_kernel(const unsigned short* __restrict__ vm,
                                                     unsigned short* __restrict__ vtt) {
  const int g = blockIdx.x, bh = g >> 3, oct = g & 7;
  const int t = threadIdx.x;
  __shared__ unsigned short tile[32][36];
  for (int s = 0; s < 4; ++s) {
    const int jt = oct * 4 + s;
    {
      int r = t >> 3, c4 = (t & 7) * 4;
      *reinterpret_cast<ushort4*>(&tile[r][c4]) = *reinterpret_cast<const ushort4*>(
          vm + ((long)bh * nN + jt * 32 + r) * 32 + c4);
    }
    __syncthreads();
    {
      int d = t >> 3, j4 = (t & 7) * 4;
      ushort4 o;
      o.x = tile[j4][d]; o.y = tile[j4 + 1][d];
      o.z = tile[j4 + 2][d]; o.w = tile[j4 + 3][d];
      *reinterpret_cast<ushort4*>(vtt + ((long)bh * 32 + jt) * 1024 + d * 32 + j4) = o;
    }
    __syncthreads();
  }
}

// ---------------- 4. fused attention (flash partials over j-chunks) ----------
// grid: x = b*32 + it, y = jc (4-way j split), z = head-group (2).
// WG = 8 waves = 8 heads sharing bias tiles in LDS.
__global__ __launch_bounds__(512, 4) void attn_kernel(
    const unsigned short* __restrict__ qm, const unsigned short* __restrict__ km,
    const unsigned short* __restrict__ vtt,
    const float* __restrict__ pdist, const float* __restrict__ angle,
    const float* __restrict__ adj, const unsigned char* __restrict__ mask,
    const float* __restrict__ gamma_p, const float* __restrict__ gamma_adj,
    const float* __restrict__ w_bias,
    unsigned short* __restrict__ po, float* __restrict__ pm, float* __restrict__ pl) {
  const int b = blockIdx.x >> 5, it = blockIdx.x & 31;
  const int jc = blockIdx.y, hg = blockIdx.z;
  const int tid = threadIdx.x, wid = tid >> 6, lane = tid & 63;
  const int h = hg * 8 + wid;
  const int li = lane & 31, hi = lane >> 5;
  const int ibase = it * 32;

  __shared__ __align__(16) float s_pd[32 * 32], s_adj[32 * 32];
  __shared__ __align__(16) float s_a0[32 * 32], s_a1[32 * 32];
  __shared__ __align__(16) float s_mkf[32];

  const float gp = gamma_p[h], ga = gamma_adj[h];
  const float wb0 = w_bias[2 * h], wb1 = w_bias[2 * h + 1];

  const unsigned short* qb = qm + ((long)(b * nH + h) * nN + ibase) * nDH;
  const bf16x8 qf0 = *reinterpret_cast<const bf16x8*>(qb + li * 32 + hi * 8);
  const bf16x8 qf1 = *reinterpret_cast<const bf16x8*>(qb + li * 32 + 16 + hi * 8);

  f32x16 o;
#pragma unroll
  for (int r = 0; r < 16; ++r) o[r] = 0.f;
  float mrun = -INFINITY, lrun = 0.f;

  for (int s = 0; s < 8; ++s) {
    const int jt = jc * 8 + s, jbase = jt * 32;
    __syncthreads();
    {  // pdist (waves 0-3) / adj (waves 4-7): 16B chunk each, XOR-swizzled
      int r = (tid >> 3) & 31, c = tid & 7;
      const float* src = (tid < 256 ? pdist : adj) +
                         ((long)b * nN + ibase + r) * nN + jbase + c * 4;
      float4 v = *reinterpret_cast<const float4*>(src);
      float* dst = (tid < 256 ? s_pd : s_adj) + r * 32 + ((c ^ (r & 7)) << 2);
      *reinterpret_cast<float4*>(dst) = v;
    }
    {  // angle: de-interleave into a0/a1, same swizzle
      int r = tid >> 4, p = tid & 15;
      float4 v = *reinterpret_cast<const float4*>(
          angle + (((long)b * nN + ibase + r) * nN + jbase + p * 2) * 2);
      int off = r * 32 + (((p >> 1) ^ (r & 7)) << 2) + (p & 1) * 2;
      *reinterpret_cast<float2*>(s_a0 + off) = make_float2(v.x, v.z);
      *reinterpret_cast<float2*>(s_a1 + off) = make_float2(v.y, v.w);
    }
    if (tid < 32) s_mkf[tid] = mask[b * nN + jbase + tid] ? -1e9f : 0.f;
    __syncthreads();

    // S^T = K_tile * Q_tile^T  (scale already folded into Q)
    const unsigned short* kb = km + ((long)(b * nH + h) * nN + jbase) * nDH;
    bf16x8 kf0 = *reinterpret_cast<const bf16x8*>(kb + li * 32 + hi * 8);
    bf16x8 kf1 = *reinterpret_cast<const bf16x8*>(kb + li * 32 + 16 + hi * 8);
    f32x16 sc;
#pragma unroll
    for (int r = 0; r < 16; ++r) sc[r] = 0.f;
    sc = __builtin_amdgcn_mfma_f32_32x32x16_bf16(kf0, qf0, sc, 0, 0, 0);
    sc = __builtin_amdgcn_mfma_f32_32x32x16_bf16(kf1, qf1, sc, 0, 0, 0);

    float sv[16];
    float tmax = -INFINITY;
#pragma unroll
    for (int g = 0; g < 4; ++g) {
      const int cs = (((2 * g + hi) ^ (li & 7)) << 2);
      f32x4 pdq = *reinterpret_cast<const f32x4*>(s_pd + li * 32 + cs);
      f32x4 adq = *reinterpret_cast<const f32x4*>(s_adj + li * 32 + cs);
      f32x4 a0q = *reinterpret_cast<const f32x4*>(s_a0 + li * 32 + cs);
      f32x4 a1q = *reinterpret_cast<const f32x4*>(s_a1 + li * 32 + cs);
      f32x4 mkq = *reinterpret_cast<const f32x4*>(s_mkf + 8 * g + 4 * hi);
#pragma unroll
      for (int u = 0; u < 4; ++u) {
        float x = sc[4 * g + u] - gp * pdq[u] + wb0 * a0q[u] + wb1 * a1q[u]
                  + ga * adq[u] + mkq[u];
        sv[4 * g + u] = x;
        tmax = fmaxf(tmax, x);
      }
    }
    tmax = fmaxf(tmax, __shfl_xor(tmax, 32));
    if (__any((int)(tmax > mrun + 8.f))) {  // T13 defer-max
      float mnew = fmaxf(mrun, tmax);
      float alpha = __expf(mrun - mnew);
      lrun *= alpha;
#pragma unroll
      for (int r = 0; r < 16; ++r) o[r] *= bperm((r & 3) + 8 * (r >> 2) + 4 * hi, alpha);
      mrun = mnew;
    }
    float psum = 0.f;
#pragma unroll
    for (int r = 0; r < 16; ++r) { sv[r] = __expf(sv[r] - mrun); psum += sv[r]; }
    psum += __shfl_xor(psum, 32);
    lrun += psum;

    // P -> bf16 A-fragments (half-exchange)
    unsigned ow[8], rw[8];
#pragma unroll
    for (int t = 0; t < 8; ++t) ow[t] = pk2(sv[2 * t], sv[2 * t + 1]);
#pragma unroll
    for (int t = 0; t < 8; ++t) rw[t] = __shfl_xor(ow[t], 32);
    union U { unsigned u[4]; bf16x8 v; };
    U u0, u1;
    if (hi == 0) {
      u0.u[0] = ow[0]; u0.u[1] = ow[1]; u0.u[2] = rw[0]; u0.u[3] = rw[1];
      u1.u[0] = ow[4]; u1.u[1] = ow[5]; u1.u[2] = rw[4]; u1.u[3] = rw[5];
    } else {
      u0.u[0] = rw[2]; u0.u[1] = rw[3]; u0.u[2] = ow[2]; u0.u[3] = ow[3];
      u1.u[0] = rw[6]; u1.u[1] = rw[7]; u1.u[2] = ow[6]; u1.u[3] = ow[7];
    }

    // PV from contiguous [d][j] tile
    const unsigned short* vb = vtt + ((long)(b * nH + h) * 32 + jt) * 1024;
    bf16x8 vf0 = *reinterpret_cast<const bf16x8*>(vb + li * 32 + hi * 8);
    bf16x8 vf1 = *reinterpret_cast<const bf16x8*>(vb + li * 32 + 16 + hi * 8);
    o = __builtin_amdgcn_mfma_f32_32x32x16_bf16(u0.v, vf0, o, 0, 0, 0);
    o = __builtin_amdgcn_mfma_f32_32x32x16_bf16(u1.v, vf1, o, 0, 0, 0);
  }

  const long task = (((long)(b * nH + h) * 32 + it) * 4 + jc);
  unsigned short* pob = po + task * 1024;
#pragma unroll
  for (int r = 0; r < 16; ++r) {
    const int irow = (r & 3) + 8 * (r >> 2) + 4 * hi;
    pob[irow * 32 + li] = f2bf(o[r]);
  }
  if (hi == 0) { pm[task * 32 + li] = mrun; pl[task * 32 + li] = lrun; }
}

// ---------------- 5b. merge j-chunk partials --------------------------------
__global__ __launch_bounds__(256) void merge_kernel(const unsigned short* __restrict__ po,
                                                    const float* __restrict__ pm,
                                                    const float* __restrict__ pl,
                                                    unsigned short* __restrict__ attb) {
  const int x = blockIdx.x;  // (b*16+h)*32+it
  const int t = threadIdx.x;
  const int i = t >> 3, d4 = (t & 7) * 4;
  const long tb = (long)x * 4;
  float m[4], l[4];
#pragma unroll
  for (int c = 0; c < 4; ++c) { m[c] = pm[(tb + c) * 32 + i]; l[c] = pl[(tb + c) * 32 + i]; }
  float M = fmaxf(fmaxf(m[0], m[1]), fmaxf(m[2], m[3]));
  float L = 0.f, w[4];
#pragma unroll
  for (int c = 0; c < 4; ++c) { w[c] = __expf(m[c] - M); L += w[c] * l[c]; }
  float o0 = 0, o1 = 0, o2 = 0, o3 = 0;
#pragma unroll
  for (int c = 0; c < 4; ++c) {
    ushort4 v = *reinterpret_cast<const ushort4*>(po + (tb + c) * 1024 + i * 32 + d4);
    o0 += w[c] * bf2f(v.x); o1 += w[c] * bf2f(v.y);
    o2 += w[c] * bf2f(v.z); o3 += w[c] * bf2f(v.w);
  }
  const float inv = 1.f / L;
  const int b = x >> 9, hh = (x >> 5) & 15, it = x & 31;
  ushort4 ov;
  ov.x = f2bf(o0 * inv); ov.y = f2bf(o1 * inv);
  ov.z = f2bf(o2 * inv); ov.w = f2bf(o3 * inv);
  *reinterpret_cast<ushort4*>(attb + ((long)b * nN + it * 32 + i) * nD + hh * 32 + d4) = ov;
}

// ---------------- 6. residual + bias + LayerNorm ----------------------------
__global__ __launch_bounds__(256) void ln_kernel(const float* __restrict__ x,
                                                 const float* __restrict__ ffc,
                                                 const float* __restrict__ ffb,
                                                 const float* __restrict__ lnw,
                                                 const float* __restrict__ lnb,
                                                 float* __restrict__ out) {
  const int row = blockIdx.x, tid = threadIdx.x;
  const int wid = tid >> 6, lane = tid & 63;
  const int c = tid * 2;
  const long base = (long)row * nD + c;
  float2 xv = *reinterpret_cast<const float2*>(x + base);
  float2 cv = *reinterpret_cast<const float2*>(ffc + base);
  float2 bv = *reinterpret_cast<const float2*>(ffb + c);
  float y0 = xv.x + cv.x + bv.x, y1 = xv.y + cv.y + bv.y;
  float s = y0 + y1, s2 = y0 * y0 + y1 * y1;
#pragma unroll
  for (int off = 1; off < 64; off <<= 1) {
    s += __shfl_xor(s, off);
    s2 += __shfl_xor(s2, off);
  }
  __shared__ float red[8];
  if (lane == 0) { red[wid] = s; red[4 + wid] = s2; }
  __syncthreads();
  s = red[0] + red[1] + red[2] + red[3];
  s2 = red[4] + red[5] + red[6] + red[7];
  const float mu = s * (1.f / nD);
  const float var = s2 * (1.f / nD) - mu * mu;
  const float rs = rsqrtf(var + 1e-5f);
  float2 wv = *reinterpret_cast<const float2*>(lnw + c);
  float2 lv = *reinterpret_cast<const float2*>(lnb + c);
  float2 ov;
  ov.x = (y0 - mu) * rs * wv.x + lv.x;
  ov.y = (y1 - mu) * rs * wv.y + lv.y;
  *reinterpret_cast<float2*>(out + base) = ov;
}

// ---------------- launch -----------------------------------------------------
extern "C" void kernel_launch(void* const* d_in, const int* in_sizes, int n_in,
                              void* d_out, int out_size, void* d_ws, size_t ws_size,
                              hipStream_t stream) {
  const float* x         = (const float*)d_in[0];
  const float* pdist     = (const float*)d_in[1];
  const float* angle     = (const float*)d_in[2];
  const float* adj       = (const float*)d_in[3];
  const unsigned char* mask = (const unsigned char*)d_in[4];
  const float* gamma_p   = (const float*)d_in[5];
  const float* gamma_adj = (const float*)d_in[6];
  const float* w_bias    = (const float*)d_in[7];
  const float* att_w     = (const float*)d_in[8];
  const float* ff_w      = (const float*)d_in[9];
  const float* ff_b      = (const float*)d_in[10];
  const float* ln_w      = (const float*)d_in[11];
  const float* ln_b      = (const float*)d_in[12];
  float* out = (float*)d_out;

  // 16 MB phase-overlaid workspace:
  //  [0x000000,0x400000) ffc (f32)        | po[0:4MB]
  //  [0x400000,0x600000) xb               | po[4:6MB]
  //  [0x600000,0x800000) vm               | po[6:8MB]
  //  [0x800000,0x980000) awb              | pm/pl (1MB)
  //  [0x980000,0xA00000) fwb
  //  [0xA00000,0xC00000) qm
  //  [0xC00000,0xE00000) km               | attb (after attn)
  //  [0xE00000,0x1000000) vtt
  char* ws = (char*)d_ws;
  float*          ffc  = (float*)(ws);
  unsigned short* xb   = (unsigned short*)(ws + 0x400000);
  unsigned short* vm   = (unsigned short*)(ws + 0x600000);
  unsigned short* awb  = (unsigned short*)(ws + 0x800000);
  unsigned short* fwb  = (unsigned short*)(ws + 0x980000);
  unsigned short* qm   = (unsigned short*)(ws + 0xA00000);
  unsigned short* km   = (unsigned short*)(ws + 0xC00000);
  unsigned short* vtt  = (unsigned short*)(ws + 0xE00000);
  unsigned short* po   = (unsigned short*)(ws);
  float*          pm   = (float*)(ws + 0x800000);
  float*          pl   = (float*)(ws + 0x880000);
  unsigned short* attb = km;

  hipLaunchKernelGGL(cvt_kernel, dim3(2048), dim3(256), 0, stream,
                     x, att_w, ff_w, xb, awb, fwb);
  hipLaunchKernelGGL((gemm_bt<64, 128, 0>), dim3(32, 12), dim3(256), 0, stream,
                     xb, awb, qm, km, vm, nullptr, 512, 0);
  hipLaunchKernelGGL(vtrans_kernel, dim3(256), dim3(256), 0, stream, vm, vtt);
  hipLaunchKernelGGL(attn_kernel, dim3(64, 4, 2), dim3(512), 0, stream,
                     qm, km, vtt, pdist, angle, adj, mask,
                     gamma_p, gamma_adj, w_bias, po, pm, pl);
  hipLaunchKernelGGL(merge_kernel, dim3(1024), dim3(256), 0, stream,
                     po, pm, pl, attb);
  hipLaunchKernelGGL((gemm_bt<64, 64, 1>), dim3(32, 8), dim3(256), 0, stream,
                     attb, fwb, nullptr, nullptr, nullptr, ffc, 512, 512);
  hipLaunchKernelGGL(ln_kernel, dim3(2048), dim3(256), 0, stream,
                     x, ffc, ff_b, ln_w, ln_b, out);
}